// Round 9
// baseline (472.817 us; speedup 1.0000x reference)
//
#include <hip/hip_runtime.h>

// NuclideGNN: 3-layer GCN on MI355X.
// R9:  block-per-node gather, LDS-staged indices, 2-deep row MLP.
// R10 (REVERTED): column-split gather -- 128B-line granularity, no win.
// R11 (REVERTED): wave-per-node -- halved MLP, BW 3.36->2.52 TB/s.
// R12 (REVERTED): scalar esrc loads put index latency on critical path.
// R13: residual chain bf16-only; -70MB/gather => gather not byte-bound.
// R14: uint4 row loads; VMEM insts x1/2 => -5%. ~1.1M L2-miss lines/8 XCD
//     /2.4GHz ~= 74us ~= measured 78 => gather L2-miss-service bound (floor).
// R15: pA_bin LDS counting-sort -> contiguous window writes (-13.4us).
// R16: buckets 256 nodes (NB=391), p4 512thr, wprep folded into inproj (-13.8us).
// R17 (REVERTED): p4+inproj+wprep mega-fusion -- +3us (neutral). Gaps cheap,
//     p4 re-read not the cost. Component model of the ~225us non-gather pool
//     is wrong somewhere -- need visibility, not more blind fusion.
// R18: R16 restored + VISIBILITY PROBE: each gather split into 2x 50k-node
//     dispatches (node-base param). Gather instances ~39us -> any hidden
//     dispatch >40us surfaces in the top-5 counter window. Perf-neutral by
//     construction (same blocks/work; ~us tail bubble).
//     Predict total ~455-465; next round targets whatever surfaces.

#define NN 100000
#define NE 3200000
#define FI 7
#define HD 128
#define DD 64
#define EPS 1e-5f
#define NB 391                        // buckets of 256 dst nodes (dst>>8)
#define EPB 8192                      // edges per pA block
#define NBLK ((NE + EPB - 1) / EPB)   // 391
#define EMAX 10000                    // fixed ebin window (max bucket ~8.7k)

typedef float float2v __attribute__((ext_vector_type(2)));
typedef short short8 __attribute__((ext_vector_type(8)));
typedef float f32x4 __attribute__((ext_vector_type(4)));
typedef unsigned uintv4 __attribute__((ext_vector_type(4)));

__device__ __forceinline__ unsigned char f2fp8(float f) {
    return (unsigned char)(__builtin_amdgcn_cvt_pk_fp8_f32(f, f, 0, false) & 0xFF);
}
__device__ __forceinline__ unsigned short f2bf(float f) {
    unsigned u = __float_as_uint(f);
    u += 0x7FFF + ((u >> 16) & 1);  // RNE
    return (unsigned short)(u >> 16);
}
__device__ __forceinline__ float bf2f(unsigned short s) {
    return __uint_as_float((unsigned)s << 16);
}

// ---------------- CSR build ----------------
// pA (R15/R16): per-block LDS counting-sort by 256-node bucket, then
// contiguous window writes. 512 threads.

__global__ __launch_bounds__(512) void pA_bin(const int* __restrict__ ei,
                                              int* __restrict__ bcnt,
                                              int* __restrict__ ebin) {
    __shared__ int rec[EPB];            // 32 KB reordered records
    __shared__ unsigned short bk[EPB];  // 16 KB bucket id per slot
    __shared__ int ls[512];             // scan buffer -> exclusive starts
    __shared__ int cur[NB];             // local cursors
    __shared__ int gb[NB];              // global window base per bucket
    __shared__ int hc[512];             // local bucket histogram
    const int t = threadIdx.x;
    const int base = blockIdx.x * EPB;
    const int cnt = min(EPB, NE - base);
    hc[t] = 0;
    __syncthreads();
    for (int i = t; i < cnt; i += 512)
        atomicAdd(&hc[ei[NE + base + i] >> 8], 1);
    __syncthreads();
    const int myc = hc[t];
    if (t < NB) gb[t] = (myc ? atomicAdd(&bcnt[t], myc) : 0) + t * EMAX;
    ls[t] = myc;
    __syncthreads();
    for (int off = 1; off < 512; off <<= 1) {
        int v = (t >= off) ? ls[t - off] : 0;
        __syncthreads();
        ls[t] += v;
        __syncthreads();
    }
    const int excl = ls[t] - myc;
    __syncthreads();
    ls[t] = excl;
    if (t < NB) cur[t] = excl;
    __syncthreads();
    // reorder records into LDS, sorted by bucket
    for (int i = t; i < cnt; i += 512) {
        int s = ei[base + i];
        int d = ei[NE + base + i];
        int b = d >> 8;
        int p = atomicAdd(&cur[b], 1);
        rec[p] = ((d & 255) << 23) | s;
        bk[p] = (unsigned short)b;
    }
    __syncthreads();
    // contiguous, single-XCD writes into each bucket's reserved run
    for (int i = t; i < cnt; i += 512) {
        int b = bk[i];
        ebin[gb[b] + (i - ls[b])] = rec[i];
    }
}

// p4: bucket-count scan (dense esrc offsets) + per-bucket hist/scan/scatter.
// R16: 391 blocks x 512 threads, 256 nodes per bucket.
__global__ __launch_bounds__(512) void p4_finalize(const int* __restrict__ bcnt,
                                                   const int* __restrict__ ebin,
                                                   int* __restrict__ esrc,
                                                   int* __restrict__ rowstart,
                                                   float* __restrict__ dinv) {
    __shared__ int sh[512];  // bucket-count scan
    __shared__ int lh[256];  // local degree
    __shared__ int sc[256];  // scan buffer
    __shared__ int lc[256];  // local cursor
    const int t = threadIdx.x;
    const int b = blockIdx.x;
    sh[t] = (t < NB) ? bcnt[t] : 0;
    __syncthreads();
    for (int off = 1; off < 512; off <<= 1) {
        int v = (t >= off) ? sh[t - off] : 0;
        __syncthreads();
        sh[t] += v;
        __syncthreads();
    }
    const int ecnt = bcnt[b];
    const int ebase = sh[b] - ecnt;   // dense esrc base for this bucket
    const int rbase = b * EMAX;       // padded ebin read base
    const int n0 = b << 8;
    if (t < 256) lh[t] = 0;
    __syncthreads();
    for (int i = t; i < ecnt; i += 512)
        atomicAdd(&lh[((unsigned)ebin[rbase + i]) >> 23], 1);
    __syncthreads();
    int c = 0;
    if (t < 256) { c = lh[t]; sc[t] = c; }
    __syncthreads();
    for (int off = 1; off < 256; off <<= 1) {
        int v = (t < 256 && t >= off) ? sc[t - off] : 0;
        __syncthreads();
        if (t < 256) sc[t] += v;
        __syncthreads();
    }
    if (t < 256) {
        const int excl = ebase + sc[t] - c;  // global rowstart for node n0+t
        lc[t] = excl;
        const int node = n0 + t;
        if (node < NN) {
            rowstart[node] = excl;
            dinv[node] = rsqrtf((float)c + 1.0f);  // deg includes self-loop
        }
    }
    if (b == NB - 1 && t == 0) rowstart[NN] = NE;
    __syncthreads();
    for (int i = t; i < ecnt; i += 512) {
        int v = ebin[rbase + i];
        int p = atomicAdd(&lc[((unsigned)v) >> 23], 1);
        esrc[p] = v & 0x7FFFFF;  // writes land in a 33KB L2-hot window
    }
}

// --------- input projection (bf16) + fused W pre-swizzle (R16) -------------
// Blocks [0, NN/2): inproj. Blocks [NN/2, NN/2+20): 80 wprep units (4/block).

__global__ __launch_bounds__(256) void inproj_wprep(const float* __restrict__ x,
                                                    const float* __restrict__ W_in,
                                                    const float* __restrict__ b_in,
                                                    unsigned short* __restrict__ hAbf,
                                                    const float* __restrict__ W0,
                                                    const float* __restrict__ W1,
                                                    const float* __restrict__ W2,
                                                    unsigned short* __restrict__ wf0,
                                                    unsigned short* __restrict__ wf1,
                                                    unsigned short* __restrict__ wf2) {
    const int blk = blockIdx.x;
    if (blk >= NN / 2) {
        const int u = (blk - NN / 2) * 4 + (threadIdx.x >> 6);
        if (u >= 80) return;
        const float* W;
        unsigned short* Wf;
        int DO, rel;
        if (u < 32) { W = W0; Wf = wf0; DO = 128; rel = u; }
        else if (u < 64) { W = W1; Wf = wf1; DO = 128; rel = u - 32; }
        else { W = W2; Wf = wf2; DO = 64; rel = u - 64; }
        const int lane = threadIdx.x & 63;
        const int nt = rel >> 2;
        const int ks = rel & 3;
        short8 o;
#pragma unroll
        for (int j = 0; j < 8; ++j)
            o[j] = (short)f2bf(W[(ks * 32 + (lane >> 4) * 8 + j) * DO + nt * 16 + (lane & 15)]);
        *(short8*)(Wf + ((size_t)rel * 64 + lane) * 8) = o;
        return;
    }
    int n = blk * 2 + (threadIdx.x >> 7);
    int j = threadIdx.x & 127;
    float acc = b_in[j];
#pragma unroll
    for (int f = 0; f < FI; ++f) acc += x[n * FI + f] * W_in[f * HD + j];
    acc = fmaxf(acc, 0.f);
    hAbf[n * HD + j] = f2bf(acc);
}

// -------- MFMA GEMM: B[N,DO](fp8) = (A[N,128](bf16) @ W) * dinv[row] --------

template <int DO>
__global__ __launch_bounds__(256) void gemm_mfma(const unsigned short* __restrict__ A,
                                                 const unsigned short* __restrict__ Wf,
                                                 const float* __restrict__ dinv,
                                                 unsigned char* __restrict__ B) {
    constexpr int CT = DO / 64;  // col-tiles per wave: 2 (DO=128) or 1 (DO=64)
    const int tid = threadIdx.x;
    const int wave = tid >> 6;
    const int lane = tid & 63;
    const int n0 = blockIdx.x * 32;
    short8 bfrag[CT][4];
#pragma unroll
    for (int ct = 0; ct < CT; ++ct)
#pragma unroll
        for (int ks = 0; ks < 4; ++ks)
            bfrag[ct][ks] = *(const short8*)(Wf + ((size_t)(((wave * CT + ct) * 4 + ks) * 64) + lane) * 8);
#pragma unroll
    for (int rt = 0; rt < 2; ++rt) {
        const int arow = n0 + rt * 16 + (lane & 15);
        short8 afrag[4];
#pragma unroll
        for (int ks = 0; ks < 4; ++ks)
            afrag[ks] = *(const short8*)(A + (size_t)arow * HD + ks * 32 + ((lane >> 4) & 3) * 8);
        f32x4 acc[CT];
#pragma unroll
        for (int ct = 0; ct < CT; ++ct) acc[ct] = (f32x4){0.f, 0.f, 0.f, 0.f};
#pragma unroll
        for (int ks = 0; ks < 4; ++ks)
#pragma unroll
            for (int ct = 0; ct < CT; ++ct)
                acc[ct] = __builtin_amdgcn_mfma_f32_16x16x32_bf16(afrag[ks], bfrag[ct][ks], acc[ct], 0, 0, 0);
#pragma unroll
        for (int r = 0; r < 4; ++r) {
            const int orow = n0 + rt * 16 + (lane >> 4) * 4 + r;
            const float dv = dinv[orow];
#pragma unroll
            for (int ct = 0; ct < CT; ++ct) {
                const int ocol = (wave * CT + ct) * 16 + (lane & 15);
                B[(size_t)orow * DO + ocol] = f2fp8(acc[ct][r] * dv);
            }
        }
    }
}

// ---------- fused gather (pure row-sum) + self-loop + bias + BN (+relu/res) --
// R14 structure; R18 adds nbase so each dispatch covers a node range
// (visibility probe: 2x 50k dispatches per layer).

template <int DO, bool RELU_RES>
__global__ __launch_bounds__(128) void gather_kernel(const unsigned char* __restrict__ hXW,
                                                     float* __restrict__ resOut,
                                                     unsigned short* __restrict__ resBf,
                                                     const int* __restrict__ rowstart,
                                                     const int* __restrict__ esrc,
                                                     const float* __restrict__ dinv,
                                                     const float* __restrict__ bias,
                                                     const float* __restrict__ g,
                                                     const float* __restrict__ be,
                                                     const float* __restrict__ m,
                                                     const float* __restrict__ v,
                                                     int nbase) {
    constexpr int CG = DO / 16;   // lanes per row: 8 (DO=128) or 4 (DO=64)
    constexpr int NG = 128 / CG;  // edge groups: 16 or 32
    __shared__ int s_idx[128];
    __shared__ float sred[16][132];  // padded: write t-major, read k*CG+q
    const int n = nbase + blockIdx.x;
    const int t = threadIdx.x;
    const int rs = rowstart[n];
    const int re = rowstart[n + 1];
    const float dn = dinv[n];
    const int q = t & (CG - 1);
    const int grp = t / CG;
    float2v aL[4], aH[4], bL[4], bH[4];
#pragma unroll
    for (int w = 0; w < 4; ++w) {
        aL[w] = (float2v){0.f, 0.f}; aH[w] = (float2v){0.f, 0.f};
        bL[w] = (float2v){0.f, 0.f}; bH[w] = (float2v){0.f, 0.f};
    }
    for (int base = rs; base < re; base += 128) {
        const int c = min(128, re - base);
        __syncthreads();
        if (t < c) s_idx[t] = esrc[base + t];
        __syncthreads();
        for (int j = grp; j < c; j += 2 * NG) {
            {
                const uintv4 u = *(const uintv4*)(hXW + (size_t)s_idx[j] * DO + q * 16);
#pragma unroll
                for (int w = 0; w < 4; ++w) {
                    aL[w] += __builtin_amdgcn_cvt_pk_f32_fp8(u[w], false);
                    aH[w] += __builtin_amdgcn_cvt_pk_f32_fp8(u[w], true);
                }
            }
            if (j + NG < c) {
                const uintv4 u = *(const uintv4*)(hXW + (size_t)s_idx[j + NG] * DO + q * 16);
#pragma unroll
                for (int w = 0; w < 4; ++w) {
                    bL[w] += __builtin_amdgcn_cvt_pk_f32_fp8(u[w], false);
                    bH[w] += __builtin_amdgcn_cvt_pk_f32_fp8(u[w], true);
                }
            }
        }
    }
#pragma unroll
    for (int w = 0; w < 4; ++w) { aL[w] += bL[w]; aH[w] += bH[w]; }
#pragma unroll
    for (int w = 0; w < 4; ++w) {
        sred[4 * w + 0][t] = aL[w].x;
        sred[4 * w + 1][t] = aL[w].y;
        sred[4 * w + 2][t] = aH[w].x;
        sred[4 * w + 3][t] = aH[w].y;
    }
    __syncthreads();
    if (t < DO) {
        // col t: held by lanes with q2 = t>>4 at slot s = t&15
        const int s = t & 15;
        const int q2 = t >> 4;
        float sum = 0.f;
#pragma unroll
        for (int k = 0; k < NG; ++k) sum += sred[s][k * CG + q2];
        // self-loop: stored row n is already dinv[n]*XW[n]
        const unsigned su = *(const unsigned*)(hXW + (size_t)n * DO + (t & ~3));
        const float2v pLo = __builtin_amdgcn_cvt_pk_f32_fp8(su, false);
        const float2v pHi = __builtin_amdgcn_cvt_pk_f32_fp8(su, true);
        const float slf = (t & 2) ? ((t & 1) ? pHi.y : pHi.x)
                                  : ((t & 1) ? pLo.y : pLo.x);
        float val = (sum + slf) * dn + bias[t];
        val = (val - m[t]) * (g[t] * rsqrtf(v[t] + EPS)) + be[t];
        if (RELU_RES) {
            val = fmaxf(val, 0.f) + bf2f(resBf[(size_t)n * DO + t]);
            resBf[(size_t)n * DO + t] = f2bf(val);
        } else {
            resOut[(size_t)n * DO + t] = val;
        }
    }
}

// ---------------- launch ----------------

extern "C" void kernel_launch(void* const* d_in, const int* in_sizes, int n_in,
                              void* d_out, int out_size, void* d_ws, size_t ws_size,
                              hipStream_t stream) {
    const float* x    = (const float*)d_in[0];
    const int*   ei   = (const int*)d_in[1];
    const float* W_in = (const float*)d_in[2];
    const float* b_in = (const float*)d_in[3];
    const float* Wl[3] = {(const float*)d_in[4], (const float*)d_in[10], (const float*)d_in[16]};
    const float* bl[3] = {(const float*)d_in[5], (const float*)d_in[11], (const float*)d_in[17]};
    const float* gl[3] = {(const float*)d_in[6], (const float*)d_in[12], (const float*)d_in[18]};
    const float* bel[3] = {(const float*)d_in[7], (const float*)d_in[13], (const float*)d_in[19]};
    const float* ml[3] = {(const float*)d_in[8], (const float*)d_in[14], (const float*)d_in[20]};
    const float* vl[3] = {(const float*)d_in[9], (const float*)d_in[15], (const float*)d_in[21]};
    float* out = (float*)d_out;

    char* ws = (char*)d_ws;
    size_t off = 0;
    auto carve = [&](size_t bytes) {
        void* p = ws + off;
        off += (bytes + 255) & ~(size_t)255;
        return p;
    };
    int*   bcnt     = (int*)carve(NB * sizeof(int));
    int*   rowstart = (int*)carve((NN + 1) * sizeof(int));
    float* dinv     = (float*)carve(NN * sizeof(float));
    int*   esrc     = (int*)carve((size_t)NE * sizeof(int));
    unsigned short* hAbf = (unsigned short*)carve((size_t)NN * HD * sizeof(unsigned short));
    unsigned char* hB = (unsigned char*)carve((size_t)NN * HD);
    int*   ebin     = (int*)carve((size_t)NB * EMAX * sizeof(int));
    unsigned short* wf0 = (unsigned short*)carve((size_t)HD * HD * sizeof(unsigned short));
    unsigned short* wf1 = (unsigned short*)carve((size_t)HD * HD * sizeof(unsigned short));
    unsigned short* wf2 = (unsigned short*)carve((size_t)HD * DD * sizeof(unsigned short));
    (void)ws_size;

    hipMemsetAsync(bcnt, 0, NB * sizeof(int), stream);

    pA_bin<<<NBLK, 512, 0, stream>>>(ei, bcnt, ebin);
    p4_finalize<<<NB, 512, 0, stream>>>(bcnt, ebin, esrc, rowstart, dinv);

    inproj_wprep<<<NN / 2 + 20, 256, 0, stream>>>(x, W_in, b_in, hAbf,
                                                  Wl[0], Wl[1], Wl[2], wf0, wf1, wf2);

    const int NH = NN / 2;  // 50000-node half-dispatches (visibility probe)
    // layer 0
    gemm_mfma<128><<<NN / 32, 256, 0, stream>>>(hAbf, wf0, dinv, hB);
    gather_kernel<128, true><<<NH, 128, 0, stream>>>(hB, (float*)nullptr, hAbf, rowstart, esrc, dinv,
                                                     bl[0], gl[0], bel[0], ml[0], vl[0], 0);
    gather_kernel<128, true><<<NH, 128, 0, stream>>>(hB, (float*)nullptr, hAbf, rowstart, esrc, dinv,
                                                     bl[0], gl[0], bel[0], ml[0], vl[0], NH);
    // layer 1
    gemm_mfma<128><<<NN / 32, 256, 0, stream>>>(hAbf, wf1, dinv, hB);
    gather_kernel<128, true><<<NH, 128, 0, stream>>>(hB, (float*)nullptr, hAbf, rowstart, esrc, dinv,
                                                     bl[1], gl[1], bel[1], ml[1], vl[1], 0);
    gather_kernel<128, true><<<NH, 128, 0, stream>>>(hB, (float*)nullptr, hAbf, rowstart, esrc, dinv,
                                                     bl[1], gl[1], bel[1], ml[1], vl[1], NH);
    // layer 2 (BN only, write d_out)
    gemm_mfma<64><<<NN / 32, 256, 0, stream>>>(hAbf, wf2, dinv, hB);
    gather_kernel<64, false><<<NH, 128, 0, stream>>>(hB, out, (unsigned short*)nullptr,
                                                     rowstart, esrc, dinv,
                                                     bl[2], gl[2], bel[2], ml[2], vl[2], 0);
    gather_kernel<64, false><<<NH, 128, 0, stream>>>(hB, out, (unsigned short*)nullptr,
                                                     rowstart, esrc, dinv,
                                                     bl[2], gl[2], bel[2], ml[2], vl[2], NH);
}

// Round 10
// 438.983 us; speedup vs baseline: 1.0771x; 1.0771x over previous
//
#include <hip/hip_runtime.h>

// NuclideGNN: 3-layer GCN on MI355X.
// R9:  block-per-node gather, LDS-staged indices, 2-deep row MLP.
// R10 (REVERTED): column-split gather -- 128B-line granularity, no win.
// R11 (REVERTED): wave-per-node -- halved MLP, BW 3.36->2.52 TB/s.
// R12 (REVERTED): scalar esrc loads put index latency on critical path.
// R13: residual chain bf16-only; -70MB/gather => gather not byte-bound.
// R14: uint4 row loads; VMEM insts x1/2 => -5%. ~1.4M L2-miss lines/8 XCD
//     /2.4GHz ~= 74us ~= measured 78 => gather L2-miss-service bound (floor).
// R15: pA_bin LDS counting-sort -> contiguous window writes (-13.4us).
// R16: buckets 256 nodes (NB=391), p4 512thr, wprep folded into inproj (-13.8us).
// R17 (REVERTED): p4+inproj+wprep mega-fusion -- neutral => gaps ~0-3us.
// R18 (probe, REVERTED): gather split 2x50k surfaced the hidden pool: harness
//     256MiB workspace re-poison fills (~43us, not ours); NO own kernel >42us.
//     Split cost +13us -> unsplit. Gather floor model confirmed at half scale.
// R19: R16 restored + int4-vectorized pA streaming reads (1/4 VMEM ops on
//     25.6MB) + inproj 8 nodes/block (12.5k blocks vs 50k). Predict ~452-460;
//     gather counters must return to FETCH~181.6MB / ~78us. If ~455: declare
//     near-roofline next (gathers at L2-miss floor; rest <=25us kernels+fill).

#define NN 100000
#define NE 3200000
#define FI 7
#define HD 128
#define DD 64
#define EPS 1e-5f
#define NB 391                        // buckets of 256 dst nodes (dst>>8)
#define EPB 8192                      // edges per pA block
#define NBLK ((NE + EPB - 1) / EPB)   // 391
#define EMAX 10000                    // fixed ebin window (max bucket ~8.7k)

typedef float float2v __attribute__((ext_vector_type(2)));
typedef short short8 __attribute__((ext_vector_type(8)));
typedef float f32x4 __attribute__((ext_vector_type(4)));
typedef unsigned uintv4 __attribute__((ext_vector_type(4)));

__device__ __forceinline__ unsigned char f2fp8(float f) {
    return (unsigned char)(__builtin_amdgcn_cvt_pk_fp8_f32(f, f, 0, false) & 0xFF);
}
__device__ __forceinline__ unsigned short f2bf(float f) {
    unsigned u = __float_as_uint(f);
    u += 0x7FFF + ((u >> 16) & 1);  // RNE
    return (unsigned short)(u >> 16);
}
__device__ __forceinline__ float bf2f(unsigned short s) {
    return __uint_as_float((unsigned)s << 16);
}

// ---------------- CSR build ----------------
// pA (R15/R16/R19): per-block LDS counting-sort by 256-node bucket, then
// contiguous window writes. 512 threads; int4 streaming reads of ei.

__global__ __launch_bounds__(512) void pA_bin(const int* __restrict__ ei,
                                              int* __restrict__ bcnt,
                                              int* __restrict__ ebin) {
    __shared__ int rec[EPB];            // 32 KB reordered records
    __shared__ unsigned short bk[EPB];  // 16 KB bucket id per slot
    __shared__ int ls[512];             // scan buffer -> exclusive starts
    __shared__ int cur[NB];             // local cursors
    __shared__ int gb[NB];              // global window base per bucket
    __shared__ int hc[512];             // local bucket histogram
    const int t = threadIdx.x;
    const int base = blockIdx.x * EPB;
    const int cnt = min(EPB, NE - base);   // always a multiple of 4
    const int cnt4 = cnt >> 2;
    hc[t] = 0;
    __syncthreads();
    {
        const int4* dp = (const int4*)(ei + NE + base);
        for (int i = t; i < cnt4; i += 512) {
            const int4 d4 = dp[i];
            atomicAdd(&hc[d4.x >> 8], 1);
            atomicAdd(&hc[d4.y >> 8], 1);
            atomicAdd(&hc[d4.z >> 8], 1);
            atomicAdd(&hc[d4.w >> 8], 1);
        }
    }
    __syncthreads();
    const int myc = hc[t];
    if (t < NB) gb[t] = (myc ? atomicAdd(&bcnt[t], myc) : 0) + t * EMAX;
    ls[t] = myc;
    __syncthreads();
    for (int off = 1; off < 512; off <<= 1) {
        int v = (t >= off) ? ls[t - off] : 0;
        __syncthreads();
        ls[t] += v;
        __syncthreads();
    }
    const int excl = ls[t] - myc;
    __syncthreads();
    ls[t] = excl;
    if (t < NB) cur[t] = excl;
    __syncthreads();
    // reorder records into LDS, sorted by bucket (int4 reads of src+dst)
    {
        const int4* sp = (const int4*)(ei + base);
        const int4* dp = (const int4*)(ei + NE + base);
        for (int i = t; i < cnt4; i += 512) {
            const int4 s4 = sp[i];
            const int4 d4 = dp[i];
#pragma unroll
            for (int k = 0; k < 4; ++k) {
                const int s = (k == 0) ? s4.x : (k == 1) ? s4.y : (k == 2) ? s4.z : s4.w;
                const int d = (k == 0) ? d4.x : (k == 1) ? d4.y : (k == 2) ? d4.z : d4.w;
                const int b = d >> 8;
                const int p = atomicAdd(&cur[b], 1);
                rec[p] = ((d & 255) << 23) | s;
                bk[p] = (unsigned short)b;
            }
        }
    }
    __syncthreads();
    // contiguous, single-XCD writes into each bucket's reserved run
    for (int i = t; i < cnt; i += 512) {
        int b = bk[i];
        ebin[gb[b] + (i - ls[b])] = rec[i];
    }
}

// p4: bucket-count scan (dense esrc offsets) + per-bucket hist/scan/scatter.
// R16: 391 blocks x 512 threads, 256 nodes per bucket.
__global__ __launch_bounds__(512) void p4_finalize(const int* __restrict__ bcnt,
                                                   const int* __restrict__ ebin,
                                                   int* __restrict__ esrc,
                                                   int* __restrict__ rowstart,
                                                   float* __restrict__ dinv) {
    __shared__ int sh[512];  // bucket-count scan
    __shared__ int lh[256];  // local degree
    __shared__ int sc[256];  // scan buffer
    __shared__ int lc[256];  // local cursor
    const int t = threadIdx.x;
    const int b = blockIdx.x;
    sh[t] = (t < NB) ? bcnt[t] : 0;
    __syncthreads();
    for (int off = 1; off < 512; off <<= 1) {
        int v = (t >= off) ? sh[t - off] : 0;
        __syncthreads();
        sh[t] += v;
        __syncthreads();
    }
    const int ecnt = bcnt[b];
    const int ebase = sh[b] - ecnt;   // dense esrc base for this bucket
    const int rbase = b * EMAX;       // padded ebin read base
    const int n0 = b << 8;
    if (t < 256) lh[t] = 0;
    __syncthreads();
    for (int i = t; i < ecnt; i += 512)
        atomicAdd(&lh[((unsigned)ebin[rbase + i]) >> 23], 1);
    __syncthreads();
    int c = 0;
    if (t < 256) { c = lh[t]; sc[t] = c; }
    __syncthreads();
    for (int off = 1; off < 256; off <<= 1) {
        int v = (t < 256 && t >= off) ? sc[t - off] : 0;
        __syncthreads();
        if (t < 256) sc[t] += v;
        __syncthreads();
    }
    if (t < 256) {
        const int excl = ebase + sc[t] - c;  // global rowstart for node n0+t
        lc[t] = excl;
        const int node = n0 + t;
        if (node < NN) {
            rowstart[node] = excl;
            dinv[node] = rsqrtf((float)c + 1.0f);  // deg includes self-loop
        }
    }
    if (b == NB - 1 && t == 0) rowstart[NN] = NE;
    __syncthreads();
    for (int i = t; i < ecnt; i += 512) {
        int v = ebin[rbase + i];
        int p = atomicAdd(&lc[((unsigned)v) >> 23], 1);
        esrc[p] = v & 0x7FFFFF;  // writes land in a 33KB L2-hot window
    }
}

// --------- input projection (bf16) + fused W pre-swizzle (R16/R19) ---------
// Blocks [0, NN/8): inproj, 8 nodes/block (col j per thread, 4 nodes each).
// Blocks [NN/8, NN/8+20): 80 wprep units (4/block).

__global__ __launch_bounds__(256) void inproj_wprep(const float* __restrict__ x,
                                                    const float* __restrict__ W_in,
                                                    const float* __restrict__ b_in,
                                                    unsigned short* __restrict__ hAbf,
                                                    const float* __restrict__ W0,
                                                    const float* __restrict__ W1,
                                                    const float* __restrict__ W2,
                                                    unsigned short* __restrict__ wf0,
                                                    unsigned short* __restrict__ wf1,
                                                    unsigned short* __restrict__ wf2) {
    const int blk = blockIdx.x;
    if (blk >= NN / 8) {
        const int u = (blk - NN / 8) * 4 + (threadIdx.x >> 6);
        if (u >= 80) return;
        const float* W;
        unsigned short* Wf;
        int DO, rel;
        if (u < 32) { W = W0; Wf = wf0; DO = 128; rel = u; }
        else if (u < 64) { W = W1; Wf = wf1; DO = 128; rel = u - 32; }
        else { W = W2; Wf = wf2; DO = 64; rel = u - 64; }
        const int lane = threadIdx.x & 63;
        const int nt = rel >> 2;
        const int ks = rel & 3;
        short8 o;
#pragma unroll
        for (int j = 0; j < 8; ++j)
            o[j] = (short)f2bf(W[(ks * 32 + (lane >> 4) * 8 + j) * DO + nt * 16 + (lane & 15)]);
        *(short8*)(Wf + ((size_t)rel * 64 + lane) * 8) = o;
        return;
    }
    const int j = threadIdx.x & 127;   // column
    const int h = threadIdx.x >> 7;    // 0..1
    float w[FI];
#pragma unroll
    for (int f = 0; f < FI; ++f) w[f] = W_in[f * HD + j];
    const float bj = b_in[j];
#pragma unroll
    for (int k = 0; k < 4; ++k) {
        const int n = blk * 8 + h * 4 + k;
        float acc = bj;
#pragma unroll
        for (int f = 0; f < FI; ++f) acc += x[n * FI + f] * w[f];
        hAbf[(size_t)n * HD + j] = f2bf(fmaxf(acc, 0.f));
    }
}

// -------- MFMA GEMM: B[N,DO](fp8) = (A[N,128](bf16) @ W) * dinv[row] --------

template <int DO>
__global__ __launch_bounds__(256) void gemm_mfma(const unsigned short* __restrict__ A,
                                                 const unsigned short* __restrict__ Wf,
                                                 const float* __restrict__ dinv,
                                                 unsigned char* __restrict__ B) {
    constexpr int CT = DO / 64;  // col-tiles per wave: 2 (DO=128) or 1 (DO=64)
    const int tid = threadIdx.x;
    const int wave = tid >> 6;
    const int lane = tid & 63;
    const int n0 = blockIdx.x * 32;
    short8 bfrag[CT][4];
#pragma unroll
    for (int ct = 0; ct < CT; ++ct)
#pragma unroll
        for (int ks = 0; ks < 4; ++ks)
            bfrag[ct][ks] = *(const short8*)(Wf + ((size_t)(((wave * CT + ct) * 4 + ks) * 64) + lane) * 8);
#pragma unroll
    for (int rt = 0; rt < 2; ++rt) {
        const int arow = n0 + rt * 16 + (lane & 15);
        short8 afrag[4];
#pragma unroll
        for (int ks = 0; ks < 4; ++ks)
            afrag[ks] = *(const short8*)(A + (size_t)arow * HD + ks * 32 + ((lane >> 4) & 3) * 8);
        f32x4 acc[CT];
#pragma unroll
        for (int ct = 0; ct < CT; ++ct) acc[ct] = (f32x4){0.f, 0.f, 0.f, 0.f};
#pragma unroll
        for (int ks = 0; ks < 4; ++ks)
#pragma unroll
            for (int ct = 0; ct < CT; ++ct)
                acc[ct] = __builtin_amdgcn_mfma_f32_16x16x32_bf16(afrag[ks], bfrag[ct][ks], acc[ct], 0, 0, 0);
#pragma unroll
        for (int r = 0; r < 4; ++r) {
            const int orow = n0 + rt * 16 + (lane >> 4) * 4 + r;
            const float dv = dinv[orow];
#pragma unroll
            for (int ct = 0; ct < CT; ++ct) {
                const int ocol = (wave * CT + ct) * 16 + (lane & 15);
                B[(size_t)orow * DO + ocol] = f2fp8(acc[ct][r] * dv);
            }
        }
    }
}

// ---------- fused gather (pure row-sum) + self-loop + bias + BN (+relu/res) --
// R14: block (128 thr) per dst node, s_idx LDS staging, 2-deep row MLP,
// uint4 (16B/lane) row loads: CG=DO/16 lanes per row, NG=128/CG edge groups.
// sred [16][132] (pad -> conflict-free), one output column per thread.

template <int DO, bool RELU_RES>
__global__ __launch_bounds__(128) void gather_kernel(const unsigned char* __restrict__ hXW,
                                                     float* __restrict__ resOut,
                                                     unsigned short* __restrict__ resBf,
                                                     const int* __restrict__ rowstart,
                                                     const int* __restrict__ esrc,
                                                     const float* __restrict__ dinv,
                                                     const float* __restrict__ bias,
                                                     const float* __restrict__ g,
                                                     const float* __restrict__ be,
                                                     const float* __restrict__ m,
                                                     const float* __restrict__ v) {
    constexpr int CG = DO / 16;   // lanes per row: 8 (DO=128) or 4 (DO=64)
    constexpr int NG = 128 / CG;  // edge groups: 16 or 32
    __shared__ int s_idx[128];
    __shared__ float sred[16][132];  // padded: write t-major, read k*CG+q
    const int n = blockIdx.x;
    const int t = threadIdx.x;
    const int rs = rowstart[n];
    const int re = rowstart[n + 1];
    const float dn = dinv[n];
    const int q = t & (CG - 1);
    const int grp = t / CG;
    float2v aL[4], aH[4], bL[4], bH[4];
#pragma unroll
    for (int w = 0; w < 4; ++w) {
        aL[w] = (float2v){0.f, 0.f}; aH[w] = (float2v){0.f, 0.f};
        bL[w] = (float2v){0.f, 0.f}; bH[w] = (float2v){0.f, 0.f};
    }
    for (int base = rs; base < re; base += 128) {
        const int c = min(128, re - base);
        __syncthreads();
        if (t < c) s_idx[t] = esrc[base + t];
        __syncthreads();
        for (int j = grp; j < c; j += 2 * NG) {
            {
                const uintv4 u = *(const uintv4*)(hXW + (size_t)s_idx[j] * DO + q * 16);
#pragma unroll
                for (int w = 0; w < 4; ++w) {
                    aL[w] += __builtin_amdgcn_cvt_pk_f32_fp8(u[w], false);
                    aH[w] += __builtin_amdgcn_cvt_pk_f32_fp8(u[w], true);
                }
            }
            if (j + NG < c) {
                const uintv4 u = *(const uintv4*)(hXW + (size_t)s_idx[j + NG] * DO + q * 16);
#pragma unroll
                for (int w = 0; w < 4; ++w) {
                    bL[w] += __builtin_amdgcn_cvt_pk_f32_fp8(u[w], false);
                    bH[w] += __builtin_amdgcn_cvt_pk_f32_fp8(u[w], true);
                }
            }
        }
    }
#pragma unroll
    for (int w = 0; w < 4; ++w) { aL[w] += bL[w]; aH[w] += bH[w]; }
#pragma unroll
    for (int w = 0; w < 4; ++w) {
        sred[4 * w + 0][t] = aL[w].x;
        sred[4 * w + 1][t] = aL[w].y;
        sred[4 * w + 2][t] = aH[w].x;
        sred[4 * w + 3][t] = aH[w].y;
    }
    __syncthreads();
    if (t < DO) {
        // col t: held by lanes with q2 = t>>4 at slot s = t&15
        const int s = t & 15;
        const int q2 = t >> 4;
        float sum = 0.f;
#pragma unroll
        for (int k = 0; k < NG; ++k) sum += sred[s][k * CG + q2];
        // self-loop: stored row n is already dinv[n]*XW[n]
        const unsigned su = *(const unsigned*)(hXW + (size_t)n * DO + (t & ~3));
        const float2v pLo = __builtin_amdgcn_cvt_pk_f32_fp8(su, false);
        const float2v pHi = __builtin_amdgcn_cvt_pk_f32_fp8(su, true);
        const float slf = (t & 2) ? ((t & 1) ? pHi.y : pHi.x)
                                  : ((t & 1) ? pLo.y : pLo.x);
        float val = (sum + slf) * dn + bias[t];
        val = (val - m[t]) * (g[t] * rsqrtf(v[t] + EPS)) + be[t];
        if (RELU_RES) {
            val = fmaxf(val, 0.f) + bf2f(resBf[(size_t)n * DO + t]);
            resBf[(size_t)n * DO + t] = f2bf(val);
        } else {
            resOut[(size_t)n * DO + t] = val;
        }
    }
}

// ---------------- launch ----------------

extern "C" void kernel_launch(void* const* d_in, const int* in_sizes, int n_in,
                              void* d_out, int out_size, void* d_ws, size_t ws_size,
                              hipStream_t stream) {
    const float* x    = (const float*)d_in[0];
    const int*   ei   = (const int*)d_in[1];
    const float* W_in = (const float*)d_in[2];
    const float* b_in = (const float*)d_in[3];
    const float* Wl[3] = {(const float*)d_in[4], (const float*)d_in[10], (const float*)d_in[16]};
    const float* bl[3] = {(const float*)d_in[5], (const float*)d_in[11], (const float*)d_in[17]};
    const float* gl[3] = {(const float*)d_in[6], (const float*)d_in[12], (const float*)d_in[18]};
    const float* bel[3] = {(const float*)d_in[7], (const float*)d_in[13], (const float*)d_in[19]};
    const float* ml[3] = {(const float*)d_in[8], (const float*)d_in[14], (const float*)d_in[20]};
    const float* vl[3] = {(const float*)d_in[9], (const float*)d_in[15], (const float*)d_in[21]};
    float* out = (float*)d_out;

    char* ws = (char*)d_ws;
    size_t off = 0;
    auto carve = [&](size_t bytes) {
        void* p = ws + off;
        off += (bytes + 255) & ~(size_t)255;
        return p;
    };
    int*   bcnt     = (int*)carve(NB * sizeof(int));
    int*   rowstart = (int*)carve((NN + 1) * sizeof(int));
    float* dinv     = (float*)carve(NN * sizeof(float));
    int*   esrc     = (int*)carve((size_t)NE * sizeof(int));
    unsigned short* hAbf = (unsigned short*)carve((size_t)NN * HD * sizeof(unsigned short));
    unsigned char* hB = (unsigned char*)carve((size_t)NN * HD);
    int*   ebin     = (int*)carve((size_t)NB * EMAX * sizeof(int));
    unsigned short* wf0 = (unsigned short*)carve((size_t)HD * HD * sizeof(unsigned short));
    unsigned short* wf1 = (unsigned short*)carve((size_t)HD * HD * sizeof(unsigned short));
    unsigned short* wf2 = (unsigned short*)carve((size_t)HD * DD * sizeof(unsigned short));
    (void)ws_size;

    hipMemsetAsync(bcnt, 0, NB * sizeof(int), stream);

    pA_bin<<<NBLK, 512, 0, stream>>>(ei, bcnt, ebin);
    p4_finalize<<<NB, 512, 0, stream>>>(bcnt, ebin, esrc, rowstart, dinv);

    inproj_wprep<<<NN / 8 + 20, 256, 0, stream>>>(x, W_in, b_in, hAbf,
                                                  Wl[0], Wl[1], Wl[2], wf0, wf1, wf2);

    // layer 0
    gemm_mfma<128><<<NN / 32, 256, 0, stream>>>(hAbf, wf0, dinv, hB);
    gather_kernel<128, true><<<NN, 128, 0, stream>>>(hB, (float*)nullptr, hAbf, rowstart, esrc, dinv,
                                                     bl[0], gl[0], bel[0], ml[0], vl[0]);
    // layer 1
    gemm_mfma<128><<<NN / 32, 256, 0, stream>>>(hAbf, wf1, dinv, hB);
    gather_kernel<128, true><<<NN, 128, 0, stream>>>(hB, (float*)nullptr, hAbf, rowstart, esrc, dinv,
                                                     bl[1], gl[1], bel[1], ml[1], vl[1]);
    // layer 2 (BN only, write d_out)
    gemm_mfma<64><<<NN / 32, 256, 0, stream>>>(hAbf, wf2, dinv, hB);
    gather_kernel<64, false><<<NN, 128, 0, stream>>>(hB, out, (unsigned short*)nullptr,
                                                     rowstart, esrc, dinv,
                                                     bl[2], gl[2], bel[2], ml[2], vl[2]);
}